// Round 1
// baseline (7937.473 us; speedup 1.0000x reference)
//
#include <hip/hip_runtime.h>

// Problem constants (from reference)
#define NN 131072          // nodes
#define NE 4194304         // edges
#define HID 8
#define BSZ 16
#define ISZ 8192
#define MDIM 1000          // lin1 out
#define ODIM 34
#define FC 128             // f-chunk per lin1 block
#define NCHUNK (65536/FC)  // 512

// ---------------- graph setup ----------------
__global__ void deg_kernel(const int* __restrict__ ei, float* __restrict__ deg) {
    int e = blockIdx.x * blockDim.x + threadIdx.x;
    if (e >= NE) return;
    int r = ei[e], c = ei[NE + e];
    if (r != c) atomicAdd(&deg[r], 1.0f);
}

__global__ void dinv_kernel(float* __restrict__ deg) {
    int n = blockIdx.x * blockDim.x + threadIdx.x;
    if (n >= NN) return;
    float d = deg[n];
    deg[n] = (d > 0.f) ? 1.0f / sqrtf(fmaxf(d, 1.0f)) : 0.0f;
}

__global__ void norm_kernel(const int* __restrict__ ei, const float* __restrict__ dinv,
                            float* __restrict__ norm) {
    int e = blockIdx.x * blockDim.x + threadIdx.x;
    if (e >= NE) return;
    int r = ei[e], c = ei[NE + e];
    norm[e] = (r != c) ? -dinv[r] * dinv[c] : 0.0f;
}

// ---------------- layer 1 (scalar features) ----------------
__global__ void scatter1(const int* __restrict__ ei, const float* __restrict__ norm,
                         const float* __restrict__ t, float* __restrict__ u) {
    int e = blockIdx.x * blockDim.x + threadIdx.x;
    if (e >= NE) return;
    float nm = norm[e];
    if (nm == 0.f) return;
    atomicAdd(&u[ei[NE + e]], nm * t[ei[e]]);
}

// Tx1 = u + diag*x
__global__ void combine1_first(const float* __restrict__ dinv, const float* __restrict__ x,
                               float* __restrict__ u) {
    int n = blockIdx.x * blockDim.x + threadIdx.x;
    if (n >= NN) return;
    float dg = (dinv[n] == 0.f) ? -1.f : 0.f;
    u[n] = u[n] + dg * x[n];
}

// Tx_k = 2*(u + diag*tprev) - tprev2
__global__ void combine1(const float* __restrict__ dinv, const float* __restrict__ tprev,
                         const float* __restrict__ tprev2, float* __restrict__ u) {
    int n = blockIdx.x * blockDim.x + threadIdx.x;
    if (n >= NN) return;
    float dg = (dinv[n] == 0.f) ? -1.f : 0.f;
    u[n] = 2.f * (u[n] + dg * tprev[n]) - tprev2[n];
}

__global__ void h1_kernel(const float* __restrict__ x,
                          const float* __restrict__ t1, const float* __restrict__ t2,
                          const float* __restrict__ t3, const float* __restrict__ t4,
                          const float* __restrict__ W1, const float* __restrict__ b1,
                          float* __restrict__ h1) {
    int n = blockIdx.x * blockDim.x + threadIdx.x;
    if (n >= NN) return;
    float v0 = x[n], v1 = t1[n], v2 = t2[n], v3 = t3[n], v4 = t4[n];
    #pragma unroll
    for (int j = 0; j < HID; ++j) {
        float s = b1[j] + v0 * W1[j] + v1 * W1[8 + j] + v2 * W1[16 + j]
                + v3 * W1[24 + j] + v4 * W1[32 + j];
        h1[n * HID + j] = fmaxf(s, 0.f);
    }
}

// ---------------- layer 2 (8-wide features) ----------------
__global__ void scatter8(const int* __restrict__ ei, const float* __restrict__ norm,
                         const float* __restrict__ t, float* __restrict__ u) {
    int e = blockIdx.x * blockDim.x + threadIdx.x;
    if (e >= NE) return;
    float nm = norm[e];
    if (nm == 0.f) return;
    int r = ei[e], c = ei[NE + e];
    const float4* tr = (const float4*)&t[r * HID];
    float4 a = tr[0], b = tr[1];
    float* uc = &u[c * HID];
    atomicAdd(uc + 0, nm * a.x); atomicAdd(uc + 1, nm * a.y);
    atomicAdd(uc + 2, nm * a.z); atomicAdd(uc + 3, nm * a.w);
    atomicAdd(uc + 4, nm * b.x); atomicAdd(uc + 5, nm * b.y);
    atomicAdd(uc + 6, nm * b.z); atomicAdd(uc + 7, nm * b.w);
}

__global__ void combine8_first(const float* __restrict__ dinv, const float* __restrict__ t,
                               float* __restrict__ u) {
    int i = blockIdx.x * blockDim.x + threadIdx.x;
    if (i >= NN * HID) return;
    int n = i >> 3;
    float dg = (dinv[n] == 0.f) ? -1.f : 0.f;
    u[i] = u[i] + dg * t[i];
}

__global__ void combine8(const float* __restrict__ dinv, const float* __restrict__ tprev,
                         const float* __restrict__ tprev2, float* __restrict__ u) {
    int i = blockIdx.x * blockDim.x + threadIdx.x;
    if (i >= NN * HID) return;
    int n = i >> 3;
    float dg = (dinv[n] == 0.f) ? -1.f : 0.f;
    u[i] = 2.f * (u[i] + dg * tprev[i]) - tprev2[i];
}

__global__ void h2_kernel(const float* __restrict__ h1,
                          const float* __restrict__ s1, const float* __restrict__ s2,
                          const float* __restrict__ s3, const float* __restrict__ s4,
                          const float* __restrict__ W2, const float* __restrict__ b2,
                          float* __restrict__ h2) {
    __shared__ float w2s[5 * 64];
    for (int i = threadIdx.x; i < 320; i += blockDim.x) w2s[i] = W2[i];
    __syncthreads();
    int n = blockIdx.x * blockDim.x + threadIdx.x;
    if (n >= NN) return;
    float in[5][HID];
    #pragma unroll
    for (int i = 0; i < HID; ++i) {
        in[0][i] = h1[n * HID + i];
        in[1][i] = s1[n * HID + i];
        in[2][i] = s2[n * HID + i];
        in[3][i] = s3[n * HID + i];
        in[4][i] = s4[n * HID + i];
    }
    #pragma unroll
    for (int j = 0; j < HID; ++j) {
        float s = b2[j];
        #pragma unroll
        for (int k = 0; k < 5; ++k)
            #pragma unroll
            for (int i = 0; i < HID; ++i)
                s = fmaf(in[k][i], w2s[k * 64 + i * 8 + j], s);
        h2[n * HID + j] = fmaxf(s, 0.f);
    }
}

// ---------------- dense layers ----------------
#define FMA4(ACC, S, WV) { ACC.x = fmaf(S, WV.x, ACC.x); ACC.y = fmaf(S, WV.y, ACC.y); \
                           ACC.z = fmaf(S, WV.z, ACC.z); ACC.w = fmaf(S, WV.w, ACC.w); }

__global__ __launch_bounds__(256) void lin1_kernel(const float* __restrict__ h2,
                                                   const float* __restrict__ w,
                                                   float* __restrict__ part) {
    int chunk = blockIdx.x;          // 0..NCHUNK-1
    int t = threadIdx.x;
    int fbase = chunk * FC;
    __shared__ __align__(16) float a[FC * 20];   // a[f][b], stride 20 for b128-aligned reads
    for (int i = t; i < BSZ * FC; i += 256) {
        int b = i / FC, f = i % FC;
        a[f * 20 + b] = h2[(size_t)b * 65536 + fbase + f];
    }
    __syncthreads();
    float4 acc[16];
    #pragma unroll
    for (int b = 0; b < 16; ++b) acc[b] = make_float4(0.f, 0.f, 0.f, 0.f);
    int m = t * 4;
    if (m < MDIM) {
        for (int f = 0; f < FC; ++f) {
            float4 wv = *(const float4*)&w[(size_t)(fbase + f) * MDIM + m];
            const float4* ar = (const float4*)&a[f * 20];
            float4 a0 = ar[0], a1 = ar[1], a2 = ar[2], a3 = ar[3];
            FMA4(acc[0], a0.x, wv) FMA4(acc[1], a0.y, wv) FMA4(acc[2], a0.z, wv) FMA4(acc[3], a0.w, wv)
            FMA4(acc[4], a1.x, wv) FMA4(acc[5], a1.y, wv) FMA4(acc[6], a1.z, wv) FMA4(acc[7], a1.w, wv)
            FMA4(acc[8], a2.x, wv) FMA4(acc[9], a2.y, wv) FMA4(acc[10], a2.z, wv) FMA4(acc[11], a2.w, wv)
            FMA4(acc[12], a3.x, wv) FMA4(acc[13], a3.y, wv) FMA4(acc[14], a3.z, wv) FMA4(acc[15], a3.w, wv)
        }
    }
    #pragma unroll
    for (int b = 0; b < 16; ++b) {
        *(float4*)&part[((size_t)chunk * 16 + b) * 1024 + m] = acc[b];
    }
}

__global__ void hidden_kernel(const float* __restrict__ part, const float* __restrict__ b1,
                              float* __restrict__ hid) {
    int i = blockIdx.x * blockDim.x + threadIdx.x;
    if (i >= BSZ * MDIM) return;
    int b = i / MDIM, m = i % MDIM;
    float s = b1[m];
    for (int c = 0; c < NCHUNK; ++c) s += part[((size_t)c * 16 + b) * 1024 + m];
    hid[(size_t)b * MDIM + m] = fmaxf(s, 0.f);
}

__global__ void out_kernel(const float* __restrict__ hid, const float* __restrict__ w2,
                           const float* __restrict__ b2, float* __restrict__ out) {
    int i = blockIdx.x * blockDim.x + threadIdx.x;
    if (i >= BSZ * ODIM) return;
    int b = i / ODIM, o = i % ODIM;
    float s = b2[o];
    for (int m = 0; m < MDIM; ++m) s = fmaf(hid[b * MDIM + m], w2[m * ODIM + o], s);
    out[i] = s;
}

extern "C" void kernel_launch(void* const* d_in, const int* in_sizes, int n_in,
                              void* d_out, int out_size, void* d_ws, size_t ws_size,
                              hipStream_t stream) {
    const float* x      = (const float*)d_in[0];
    const int*   ei     = (const int*)d_in[1];
    const float* W1     = (const float*)d_in[4];
    const float* b1     = (const float*)d_in[5];
    const float* W2     = (const float*)d_in[6];
    const float* b2     = (const float*)d_in[7];
    const float* lin1w  = (const float*)d_in[8];
    const float* lin1b  = (const float*)d_in[9];
    const float* lin2w  = (const float*)d_in[10];
    const float* lin2b  = (const float*)d_in[11];
    float* out = (float*)d_out;

    float* ws = (float*)d_ws;
    const size_t N = NN, E = NE;
    float* dinv = ws;                 // N
    float* h1   = dinv + N;           // 8N
    float* h2   = h1 + 8 * N;         // 8N
    float* hid  = h2 + 8 * N;         // 16384
    float* norm = hid + 16384;        // E
    float* t1 = norm + E;             // N each
    float* t2 = t1 + N;
    float* t3 = t2 + N;
    float* t4 = t3 + N;
    float* s1 = t4 + N;               // 8N each
    float* s2 = s1 + 8 * N;
    float* s3 = s2 + 8 * N;
    float* s4 = s3 + 8 * N;
    float* part = norm;               // alias: dead region by lin1 time; 512*16*1024 floats

    const int TB = 256;
    const int GE = NE / TB;           // 16384
    const int GN = NN / TB;           // 512
    const int GN8 = NN * HID / TB;    // 4096

    // setup
    hipMemsetAsync(dinv, 0, N * 4, stream);
    deg_kernel<<<GE, TB, 0, stream>>>(ei, dinv);
    dinv_kernel<<<GN, TB, 0, stream>>>(dinv);
    norm_kernel<<<GE, TB, 0, stream>>>(ei, dinv, norm);

    // layer 1
    hipMemsetAsync(t1, 0, N * 4, stream);
    scatter1<<<GE, TB, 0, stream>>>(ei, norm, x, t1);
    combine1_first<<<GN, TB, 0, stream>>>(dinv, x, t1);
    hipMemsetAsync(t2, 0, N * 4, stream);
    scatter1<<<GE, TB, 0, stream>>>(ei, norm, t1, t2);
    combine1<<<GN, TB, 0, stream>>>(dinv, t1, x, t2);
    hipMemsetAsync(t3, 0, N * 4, stream);
    scatter1<<<GE, TB, 0, stream>>>(ei, norm, t2, t3);
    combine1<<<GN, TB, 0, stream>>>(dinv, t2, t1, t3);
    hipMemsetAsync(t4, 0, N * 4, stream);
    scatter1<<<GE, TB, 0, stream>>>(ei, norm, t3, t4);
    combine1<<<GN, TB, 0, stream>>>(dinv, t3, t2, t4);
    h1_kernel<<<GN, TB, 0, stream>>>(x, t1, t2, t3, t4, W1, b1, h1);

    // layer 2
    hipMemsetAsync(s1, 0, N * HID * 4, stream);
    scatter8<<<GE, TB, 0, stream>>>(ei, norm, h1, s1);
    combine8_first<<<GN8, TB, 0, stream>>>(dinv, h1, s1);
    hipMemsetAsync(s2, 0, N * HID * 4, stream);
    scatter8<<<GE, TB, 0, stream>>>(ei, norm, s1, s2);
    combine8<<<GN8, TB, 0, stream>>>(dinv, s1, h1, s2);
    hipMemsetAsync(s3, 0, N * HID * 4, stream);
    scatter8<<<GE, TB, 0, stream>>>(ei, norm, s2, s3);
    combine8<<<GN8, TB, 0, stream>>>(dinv, s2, s1, s3);
    hipMemsetAsync(s4, 0, N * HID * 4, stream);
    scatter8<<<GE, TB, 0, stream>>>(ei, norm, s3, s4);
    combine8<<<GN8, TB, 0, stream>>>(dinv, s3, s2, s4);
    h2_kernel<<<GN, TB, 0, stream>>>(h1, s1, s2, s3, s4, W2, b2, h2);

    // dense
    lin1_kernel<<<NCHUNK, TB, 0, stream>>>(h2, lin1w, part);
    hidden_kernel<<<(BSZ * MDIM + TB - 1) / TB, TB, 0, stream>>>(part, lin1b, hid);
    out_kernel<<<(BSZ * ODIM + TB - 1) / TB, TB, 0, stream>>>(hid, lin2w, lin2b, out);
}

// Round 2
// 1448.207 us; speedup vs baseline: 5.4809x; 5.4809x over previous
//
#include <hip/hip_runtime.h>

#define NN 131072          // nodes
#define NE 4194304         // edges
#define HID 8
#define BSZ 16
#define MDIM 1000
#define ODIM 34
#define FC 256             // f-chunk per lin1 block
#define NCHUNK 256         // 65536 / FC

// ---------------- CSR build ----------------
// deg by row (out-degree, reference's segment_sum(w,row)); cnt by col (CSR bucket sizes).
// All r!=c edges go in the CSR: dinv factors zero out contributions from deg-0 endpoints.
__global__ void degcount_kernel(const int* __restrict__ ei, int* __restrict__ deg,
                                int* __restrict__ cnt) {
    int e = blockIdx.x * blockDim.x + threadIdx.x;
    if (e >= NE) return;
    int r = ei[e], c = ei[NE + e];
    if (r != c) {
        atomicAdd(&deg[r], 1);
        atomicAdd(&cnt[c], 1);
    }
}

__global__ void dinv_kernel(const int* __restrict__ deg, float* __restrict__ dinv) {
    int n = blockIdx.x * blockDim.x + threadIdx.x;
    if (n >= NN) return;
    int d = deg[n];
    dinv[n] = (d > 0) ? 1.0f / sqrtf((float)d) : 0.0f;
}

// single-block exclusive scan of cnt[NN] -> ptr (start) and pos (fill cursor)
__global__ __launch_bounds__(1024) void scan_kernel(const int* __restrict__ cnt,
                                                    int* __restrict__ ptr,
                                                    int* __restrict__ pos) {
    __shared__ int sums[1024];
    int t = threadIdx.x;
    int base = t * 128;
    int s = 0;
    for (int i = 0; i < 128; ++i) s += cnt[base + i];
    sums[t] = s;
    __syncthreads();
    for (int off = 1; off < 1024; off <<= 1) {
        int v = (t >= off) ? sums[t - off] : 0;
        __syncthreads();
        sums[t] += v;
        __syncthreads();
    }
    int run = sums[t] - s;   // exclusive base for this thread's segment
    for (int i = 0; i < 128; ++i) {
        ptr[base + i] = run;
        pos[base + i] = run;
        run += cnt[base + i];
    }
}

__global__ void fill_kernel(const int* __restrict__ ei, int* __restrict__ pos,
                            int* __restrict__ srcv) {
    int e = blockIdx.x * blockDim.x + threadIdx.x;
    if (e >= NE) return;
    int r = ei[e], c = ei[NE + e];
    if (r != c) {
        int p = atomicAdd(&pos[c], 1);
        srcv[p] = r;
    }
}

// ---------------- layer 1 (scalar features), gather form ----------------
// lhat(t)[n] = -dinv[n] * sum_{e: col=n} dinv[src]*t[src] + diag[n]*t[n]
template <int MODE>   // 0: Tx1 = lhat(t);  1: Tx = 2*lhat(t) - tprev2
__global__ void cheb1_pass(const int* __restrict__ ptr, const int* __restrict__ pend,
                           const int* __restrict__ srcv, const float* __restrict__ dinv,
                           const float* __restrict__ t, const float* __restrict__ tprev2,
                           float* __restrict__ u) {
    int n = blockIdx.x * blockDim.x + threadIdx.x;
    if (n >= NN) return;
    int e0 = ptr[n], e1 = pend[n];
    float a = 0.f;
    for (int i = e0; i < e1; ++i) {
        int s = srcv[i];
        a = fmaf(dinv[s], t[s], a);
    }
    float dn = dinv[n];
    float dg = (dn == 0.f) ? -1.f : 0.f;
    float lh = -dn * a + dg * t[n];
    u[n] = (MODE == 0) ? lh : 2.f * lh - tprev2[n];
}

__global__ void h1_kernel(const float* __restrict__ x,
                          const float* __restrict__ t1, const float* __restrict__ t2,
                          const float* __restrict__ t3, const float* __restrict__ t4,
                          const float* __restrict__ W1, const float* __restrict__ b1,
                          float* __restrict__ h1) {
    int n = blockIdx.x * blockDim.x + threadIdx.x;
    if (n >= NN) return;
    float v0 = x[n], v1 = t1[n], v2 = t2[n], v3 = t3[n], v4 = t4[n];
    #pragma unroll
    for (int j = 0; j < HID; ++j) {
        float s = b1[j] + v0 * W1[j] + v1 * W1[8 + j] + v2 * W1[16 + j]
                + v3 * W1[24 + j] + v4 * W1[32 + j];
        h1[n * HID + j] = fmaxf(s, 0.f);
    }
}

// ---------------- layer 2 (8-wide), gather + fused W2[k] accumulation ----------------
// acc init: acc[n][o] = b2[o] + sum_j h1[n][j] * W2[0][j][o]
__global__ void acc_init_kernel(const float* __restrict__ h1, const float* __restrict__ W20,
                                const float* __restrict__ b2, float* __restrict__ acc) {
    int gid = blockIdx.x * blockDim.x + threadIdx.x;
    if (gid >= NN * HID) return;
    int n = gid >> 3, o = gid & 7;
    float s = b2[o];
    #pragma unroll
    for (int j = 0; j < HID; ++j) s = fmaf(h1[n * HID + j], W20[j * 8 + o], s);
    acc[gid] = s;
}

// 8 lanes per node (lane j = feature). MODE: 0 first (Tx1), 1 mid, 2 final (relu, no T store)
template <int MODE>
__global__ __launch_bounds__(256) void cheb8_pass(
        const int* __restrict__ ptr, const int* __restrict__ pend,
        const int* __restrict__ srcv, const float* __restrict__ dinv,
        const float* __restrict__ t, const float* __restrict__ tprev2,
        float* __restrict__ u, const float* __restrict__ Wk, float* __restrict__ acc) {
    __shared__ float tl[32][HID];
    __shared__ float wk[64];
    int tid = threadIdx.x;
    if (tid < 64) wk[tid] = Wk[tid];
    int gid = blockIdx.x * 256 + tid;
    int n = gid >> 3, j = gid & 7;
    int e0 = ptr[n], e1 = pend[n];
    float a = 0.f;
    for (int i = e0; i < e1; ++i) {
        int s = srcv[i];
        a = fmaf(dinv[s], t[s * HID + j], a);
    }
    float dn = dinv[n];
    float dg = (dn == 0.f) ? -1.f : 0.f;
    float lh = -dn * a + dg * t[n * HID + j];
    float v = (MODE == 0) ? lh : 2.f * lh - tprev2[n * HID + j];
    if (MODE != 2) u[n * HID + j] = v;
    int nl = tid >> 3;
    tl[nl][j] = v;
    __syncthreads();
    float s = 0.f;
    #pragma unroll
    for (int jj = 0; jj < HID; ++jj) s = fmaf(tl[nl][jj], wk[jj * 8 + j], s);
    float r = acc[gid] + s;
    acc[gid] = (MODE == 2) ? fmaxf(r, 0.f) : r;
}

// ---------------- dense layers ----------------
#define FMA4(ACC, S, WV) { ACC.x = fmaf(S, WV.x, ACC.x); ACC.y = fmaf(S, WV.y, ACC.y); \
                           ACC.z = fmaf(S, WV.z, ACC.z); ACC.w = fmaf(S, WV.w, ACC.w); }

__global__ __launch_bounds__(256) void lin1_kernel(const float* __restrict__ h2,
                                                   const float* __restrict__ w,
                                                   float* __restrict__ part) {
    int chunk = blockIdx.x;          // 0..NCHUNK-1
    int t = threadIdx.x;
    int fbase = chunk * FC;
    __shared__ __align__(16) float a[FC * 20];
    for (int i = t; i < BSZ * FC; i += 256) {
        int b = i / FC, f = i % FC;
        a[f * 20 + b] = h2[(size_t)b * 65536 + fbase + f];
    }
    __syncthreads();
    float4 acc[16];
    #pragma unroll
    for (int b = 0; b < 16; ++b) acc[b] = make_float4(0.f, 0.f, 0.f, 0.f);
    int m = t * 4;
    if (m < MDIM) {
        for (int f = 0; f < FC; ++f) {
            float4 wv = *(const float4*)&w[(size_t)(fbase + f) * MDIM + m];
            const float4* ar = (const float4*)&a[f * 20];
            float4 a0 = ar[0], a1 = ar[1], a2 = ar[2], a3 = ar[3];
            FMA4(acc[0], a0.x, wv) FMA4(acc[1], a0.y, wv) FMA4(acc[2], a0.z, wv) FMA4(acc[3], a0.w, wv)
            FMA4(acc[4], a1.x, wv) FMA4(acc[5], a1.y, wv) FMA4(acc[6], a1.z, wv) FMA4(acc[7], a1.w, wv)
            FMA4(acc[8], a2.x, wv) FMA4(acc[9], a2.y, wv) FMA4(acc[10], a2.z, wv) FMA4(acc[11], a2.w, wv)
            FMA4(acc[12], a3.x, wv) FMA4(acc[13], a3.y, wv) FMA4(acc[14], a3.z, wv) FMA4(acc[15], a3.w, wv)
        }
    }
    #pragma unroll
    for (int b = 0; b < 16; ++b) {
        *(float4*)&part[((size_t)chunk * 16 + b) * 1024 + m] = acc[b];
    }
}

__global__ void hidden_kernel(const float* __restrict__ part, const float* __restrict__ b1,
                              float* __restrict__ hid) {
    int i = blockIdx.x * blockDim.x + threadIdx.x;
    if (i >= BSZ * MDIM) return;
    int b = i / MDIM, m = i % MDIM;
    float s = b1[m];
    for (int c = 0; c < NCHUNK; ++c) s += part[((size_t)c * 16 + b) * 1024 + m];
    hid[(size_t)b * MDIM + m] = fmaxf(s, 0.f);
}

__global__ void out_kernel(const float* __restrict__ hid, const float* __restrict__ w2,
                           const float* __restrict__ b2, float* __restrict__ out) {
    int i = blockIdx.x * blockDim.x + threadIdx.x;
    if (i >= BSZ * ODIM) return;
    int b = i / ODIM, o = i % ODIM;
    float s = b2[o];
    for (int m = 0; m < MDIM; ++m) s = fmaf(hid[b * MDIM + m], w2[m * ODIM + o], s);
    out[i] = s;
}

extern "C" void kernel_launch(void* const* d_in, const int* in_sizes, int n_in,
                              void* d_out, int out_size, void* d_ws, size_t ws_size,
                              hipStream_t stream) {
    const float* x      = (const float*)d_in[0];
    const int*   ei     = (const int*)d_in[1];
    const float* W1     = (const float*)d_in[4];
    const float* b1     = (const float*)d_in[5];
    const float* W2     = (const float*)d_in[6];
    const float* b2     = (const float*)d_in[7];
    const float* lin1w  = (const float*)d_in[8];
    const float* lin1b  = (const float*)d_in[9];
    const float* lin2w  = (const float*)d_in[10];
    const float* lin2b  = (const float*)d_in[11];
    float* out = (float*)d_out;

    // workspace layout (floats). Total ~36 MB.
    float* ws   = (float*)d_ws;
    float* dinv = ws;                      // NN
    int*   degi = (int*)(dinv + NN);       // NN
    int*   cnt  = degi + NN;               // NN
    int*   ptrA = cnt + NN;                // NN
    int*   posA = ptrA + NN;               // NN
    float* t1   = (float*)(posA + NN);     // NN
    float* t2   = t1 + NN;                 // NN
    float* t3   = t2 + NN;                 // NN
    float* t4   = t3 + NN;                 // NN
    float* h1   = t4 + NN;                 // 8*NN
    float* bufA = h1 + 8 * (size_t)NN;     // 8*NN
    float* bufB = bufA + 8 * (size_t)NN;   // 8*NN
    float* acc  = bufB + 8 * (size_t)NN;   // 8*NN  (becomes h2 in place)
    float* hid  = acc + 8 * (size_t)NN;    // 16384
    int*   srcv = (int*)(hid + 16384);     // NE     (dead by lin1 time)
    float* part = (float*)srcv;            // alias: NCHUNK*16*1024 = NE floats

    const int TB = 256;
    const int GE  = NE / TB;               // 16384
    const int GN  = NN / TB;               // 512
    const int GN8 = NN * HID / TB;         // 4096

    // CSR build
    hipMemsetAsync(degi, 0, NN * sizeof(int), stream);
    hipMemsetAsync(cnt, 0, NN * sizeof(int), stream);
    degcount_kernel<<<GE, TB, 0, stream>>>(ei, degi, cnt);
    dinv_kernel<<<GN, TB, 0, stream>>>(degi, dinv);
    scan_kernel<<<1, 1024, 0, stream>>>(cnt, ptrA, posA);
    fill_kernel<<<GE, TB, 0, stream>>>(ei, posA, srcv);

    // layer 1 (Chebyshev on scalar features)
    cheb1_pass<0><<<GN, TB, 0, stream>>>(ptrA, posA, srcv, dinv, x, nullptr, t1);
    cheb1_pass<1><<<GN, TB, 0, stream>>>(ptrA, posA, srcv, dinv, t1, x, t2);
    cheb1_pass<1><<<GN, TB, 0, stream>>>(ptrA, posA, srcv, dinv, t2, t1, t3);
    cheb1_pass<1><<<GN, TB, 0, stream>>>(ptrA, posA, srcv, dinv, t3, t2, t4);
    h1_kernel<<<GN, TB, 0, stream>>>(x, t1, t2, t3, t4, W1, b1, h1);

    // layer 2 (Chebyshev on 8-wide features, fused W2[k] accumulation)
    acc_init_kernel<<<GN8, TB, 0, stream>>>(h1, W2, b2, acc);
    cheb8_pass<0><<<GN8, TB, 0, stream>>>(ptrA, posA, srcv, dinv, h1, nullptr, bufA, W2 + 64, acc);
    cheb8_pass<1><<<GN8, TB, 0, stream>>>(ptrA, posA, srcv, dinv, bufA, h1, bufB, W2 + 128, acc);
    cheb8_pass<1><<<GN8, TB, 0, stream>>>(ptrA, posA, srcv, dinv, bufB, bufA, bufA, W2 + 192, acc);
    cheb8_pass<2><<<GN8, TB, 0, stream>>>(ptrA, posA, srcv, dinv, bufA, bufB, nullptr, W2 + 256, acc);
    // acc now holds h2 = relu(cheb2 output)

    // dense
    lin1_kernel<<<NCHUNK, TB, 0, stream>>>(acc, lin1w, part);
    hidden_kernel<<<(BSZ * MDIM + TB - 1) / TB, TB, 0, stream>>>(part, lin1b, hid);
    out_kernel<<<(BSZ * ODIM + TB - 1) / TB, TB, 0, stream>>>(hid, lin2w, lin2b, out);
}

// Round 3
// 1151.155 us; speedup vs baseline: 6.8952x; 1.2580x over previous
//
#include <hip/hip_runtime.h>

#define NN 131072          // nodes (2^17)
#define NE 4194304         // edges
#define HID 8
#define BSZ 16
#define MDIM 1000
#define ODIM 34
#define FC 256             // f-chunk per lin1 block
#define NCHUNK 256         // 65536 / FC

#define NB 512             // edge-stripe blocks for binning
#define EPB (NE / NB)      // 8192 edges per stripe
#define NBUK 1024          // col buckets (128 nodes each)
#define CNOD 128           // nodes per col bucket
#define NBUKR 512          // row buckets (256 nodes each)

// ---------------- binning build (no global atomics) ----------------
__global__ __launch_bounds__(256) void bin_count(const int* __restrict__ ei,
                                                 int* __restrict__ colhist,
                                                 int* __restrict__ rowhist) {
    __shared__ int ch[NBUK];
    __shared__ int rh[NBUKR];
    int b = blockIdx.x, t = threadIdx.x;
    for (int i = t; i < NBUK; i += 256) ch[i] = 0;
    for (int i = t; i < NBUKR; i += 256) rh[i] = 0;
    __syncthreads();
    int base = b * EPB;
    for (int k = 0; k < EPB; k += 256) {
        int e = base + k + t;
        int r = ei[e], c = ei[NE + e];
        if (r != c) {
            atomicAdd(&ch[c >> 7], 1);
            atomicAdd(&rh[r >> 8], 1);
        }
    }
    __syncthreads();
    for (int i = t; i < NBUK; i += 256) colhist[(size_t)i * NB + b] = ch[i];
    for (int i = t; i < NBUKR; i += 256) rowhist[(size_t)i * NB + b] = rh[i];
}

// in-place exclusive scan of hist[bucket][0..NB) -> offsets; tot[bucket] = sum
__global__ __launch_bounds__(256) void bin_scan(int* __restrict__ hist, int* __restrict__ tot) {
    __shared__ int s[256];
    int b = blockIdx.x, t = threadIdx.x;
    int* h = hist + (size_t)b * NB;
    int a0 = h[2 * t], a1 = h[2 * t + 1];
    int ps = a0 + a1;
    s[t] = ps; __syncthreads();
    for (int off = 1; off < 256; off <<= 1) {
        int x = (t >= off) ? s[t - off] : 0;
        __syncthreads(); s[t] += x; __syncthreads();
    }
    int excl = s[t] - ps;
    h[2 * t] = excl; h[2 * t + 1] = excl + a0;
    if (t == 255) tot[b] = excl + ps;
}

// exclusive scan of tot[256*M] -> basev (single block)
template <int M>
__global__ __launch_bounds__(256) void base_scan(const int* __restrict__ tot,
                                                 int* __restrict__ basev) {
    __shared__ int s[256];
    int t = threadIdx.x;
    int v[M]; int ps = 0;
    #pragma unroll
    for (int q = 0; q < M; ++q) { v[q] = tot[t * M + q]; ps += v[q]; }
    s[t] = ps; __syncthreads();
    for (int off = 1; off < 256; off <<= 1) {
        int x = (t >= off) ? s[t - off] : 0;
        __syncthreads(); s[t] += x; __syncthreads();
    }
    int run = s[t] - ps;
    #pragma unroll
    for (int q = 0; q < M; ++q) { basev[t * M + q] = run; run += v[q]; }
}

__global__ __launch_bounds__(256) void bin_fill(const int* __restrict__ ei,
                                                const int* __restrict__ colhist,
                                                const int* __restrict__ rowhist,
                                                const int* __restrict__ colbase,
                                                const int* __restrict__ rowbase,
                                                unsigned int* __restrict__ colbinned,
                                                unsigned char* __restrict__ rowbinned) {
    __shared__ int cc[NBUK];
    __shared__ int rc[NBUKR];
    int b = blockIdx.x, t = threadIdx.x;
    for (int i = t; i < NBUK; i += 256) cc[i] = colbase[i] + colhist[(size_t)i * NB + b];
    for (int i = t; i < NBUKR; i += 256) rc[i] = rowbase[i] + rowhist[(size_t)i * NB + b];
    __syncthreads();
    int base = b * EPB;
    for (int k = 0; k < EPB; k += 256) {
        int e = base + k + t;
        int r = ei[e], c = ei[NE + e];
        if (r != c) {
            int p = atomicAdd(&cc[c >> 7], 1);
            colbinned[p] = ((unsigned)r << 7) | (unsigned)(c & 127);
            int q = atomicAdd(&rc[r >> 8], 1);
            rowbinned[q] = (unsigned char)(r & 255);
        }
    }
}

// per-row-bucket degree histogram -> dinv (no global atomics)
__global__ __launch_bounds__(256) void deg_finish(const unsigned char* __restrict__ rowbinned,
                                                  const int* __restrict__ rowbase,
                                                  const int* __restrict__ rowtot,
                                                  float* __restrict__ dinv) {
    __shared__ int cnt[256];
    int b = blockIdx.x, t = threadIdx.x;
    cnt[t] = 0; __syncthreads();
    int s0 = rowbase[b], n = rowtot[b];
    for (int i = t; i < n; i += 256) atomicAdd(&cnt[rowbinned[s0 + i]], 1);
    __syncthreads();
    int d = cnt[t];
    dinv[b * 256 + t] = (d > 0) ? rsqrtf((float)d) : 0.f;
}

// ---------------- layer 1 (scalar), per-bucket LDS accumulation ----------------
template <int MODE>   // 0: Tx1 = lhat(t);  1: Tx = 2*lhat(t) - tp2
__global__ __launch_bounds__(256) void cheb1_b(const unsigned int* __restrict__ colbinned,
                                               const int* __restrict__ colbase,
                                               const int* __restrict__ coltot,
                                               const float* __restrict__ dinv,
                                               const float* __restrict__ t,
                                               const float* __restrict__ tp2,
                                               float* __restrict__ u) {
    __shared__ float acc[CNOD];
    int b = blockIdx.x, tid = threadIdx.x;
    if (tid < CNOD) acc[tid] = 0.f;
    __syncthreads();
    int s0 = colbase[b], n = coltot[b];
    for (int i = tid; i < n; i += 256) {
        unsigned int rec = colbinned[s0 + i];
        int r = rec >> 7, cl = rec & 127;
        atomicAdd(&acc[cl], dinv[r] * t[r]);
    }
    __syncthreads();
    if (tid < CNOD) {
        int node = b * CNOD + tid;
        float dn = dinv[node];
        float dg = (dn == 0.f) ? -1.f : 0.f;
        float lh = -dn * acc[tid] + dg * t[node];
        u[node] = (MODE == 0) ? lh : 2.f * lh - tp2[node];
    }
}

__global__ void h1_kernel(const float* __restrict__ x,
                          const float* __restrict__ t1, const float* __restrict__ t2,
                          const float* __restrict__ t3, const float* __restrict__ t4,
                          const float* __restrict__ W1, const float* __restrict__ b1,
                          float* __restrict__ h1) {
    int n = blockIdx.x * blockDim.x + threadIdx.x;
    if (n >= NN) return;
    float v0 = x[n], v1 = t1[n], v2 = t2[n], v3 = t3[n], v4 = t4[n];
    #pragma unroll
    for (int j = 0; j < HID; ++j) {
        float s = b1[j] + v0 * W1[j] + v1 * W1[8 + j] + v2 * W1[16 + j]
                + v3 * W1[24 + j] + v4 * W1[32 + j];
        h1[n * HID + j] = fmaxf(s, 0.f);
    }
}

// acc init: acc[n][o] = b2[o] + sum_j h1[n][j] * W2[0][j][o]
__global__ void acc_init_kernel(const float* __restrict__ h1, const float* __restrict__ W20,
                                const float* __restrict__ b2, float* __restrict__ acc) {
    int gid = blockIdx.x * blockDim.x + threadIdx.x;
    if (gid >= NN * HID) return;
    int n = gid >> 3, o = gid & 7;
    float s = b2[o];
    #pragma unroll
    for (int j = 0; j < HID; ++j) s = fmaf(h1[n * HID + j], W20[j * 8 + o], s);
    acc[gid] = s;
}

// ---------------- layer 2 (8-wide), per-bucket LDS accumulation + fused W2[k] ----------------
template <int MODE>   // 0 first, 1 mid, 2 final (relu into accg, no u store)
__global__ __launch_bounds__(256) void cheb8_b(const unsigned int* __restrict__ colbinned,
                                               const int* __restrict__ colbase,
                                               const int* __restrict__ coltot,
                                               const float* __restrict__ dinv,
                                               const float* __restrict__ t,
                                               const float* __restrict__ tp2,
                                               float* __restrict__ u,
                                               const float* __restrict__ Wk,
                                               float* __restrict__ accg) {
    __shared__ float acc[CNOD * HID];   // 4 KB
    __shared__ float wk[64];
    int b = blockIdx.x, tid = threadIdx.x;
    if (tid < 64) wk[tid] = Wk[tid];
    for (int i = tid; i < CNOD * HID; i += 256) acc[i] = 0.f;
    __syncthreads();
    int s0 = colbase[b], n = coltot[b];
    int j = tid & 7;
    for (int i = (tid >> 3); i < n; i += 32) {
        unsigned int rec = colbinned[s0 + i];
        int r = rec >> 7, cl = rec & 127;
        atomicAdd(&acc[cl * HID + j], dinv[r] * t[r * HID + j]);
    }
    __syncthreads();
    // combine: v = (MODE==0) ? lhat : 2*lhat - tp2 ; store u; stage v in LDS
    float vloc[4];
    #pragma unroll
    for (int k2 = 0; k2 < 4; ++k2) {
        int idx = k2 * 256 + tid;          // 0..1023
        int nl = idx >> 3, jj = idx & 7;
        int node = b * CNOD + nl;
        float dn = dinv[node];
        float dg = (dn == 0.f) ? -1.f : 0.f;
        float lh = -dn * acc[idx] + dg * t[node * HID + jj];
        float v = (MODE == 0) ? lh : 2.f * lh - tp2[node * HID + jj];
        vloc[k2] = v;
        if (MODE != 2) u[node * HID + jj] = v;
    }
    __syncthreads();
    #pragma unroll
    for (int k2 = 0; k2 < 4; ++k2) acc[k2 * 256 + tid] = vloc[k2];
    __syncthreads();
    // accg += v @ Wk  (relu at final)
    #pragma unroll
    for (int k2 = 0; k2 < 4; ++k2) {
        int idx = k2 * 256 + tid;
        int nl = idx >> 3, jj = idx & 7;
        float s = 0.f;
        #pragma unroll
        for (int q = 0; q < HID; ++q) s = fmaf(acc[nl * HID + q], wk[q * 8 + jj], s);
        int node = b * CNOD + nl;
        float rres = accg[node * HID + jj] + s;
        accg[node * HID + jj] = (MODE == 2) ? fmaxf(rres, 0.f) : rres;
    }
}

// ---------------- dense layers ----------------
#define FMA4(ACC, S, WV) { ACC.x = fmaf(S, WV.x, ACC.x); ACC.y = fmaf(S, WV.y, ACC.y); \
                           ACC.z = fmaf(S, WV.z, ACC.z); ACC.w = fmaf(S, WV.w, ACC.w); }

__global__ __launch_bounds__(256) void lin1_kernel(const float* __restrict__ h2,
                                                   const float* __restrict__ w,
                                                   float* __restrict__ part) {
    int chunk = blockIdx.x;
    int t = threadIdx.x;
    int fbase = chunk * FC;
    __shared__ __align__(16) float a[FC * 20];
    for (int i = t; i < BSZ * FC; i += 256) {
        int b = i / FC, f = i % FC;
        a[f * 20 + b] = h2[(size_t)b * 65536 + fbase + f];
    }
    __syncthreads();
    float4 acc[16];
    #pragma unroll
    for (int b = 0; b < 16; ++b) acc[b] = make_float4(0.f, 0.f, 0.f, 0.f);
    int m = t * 4;
    if (m < MDIM) {
        for (int f = 0; f < FC; ++f) {
            float4 wv = *(const float4*)&w[(size_t)(fbase + f) * MDIM + m];
            const float4* ar = (const float4*)&a[f * 20];
            float4 a0 = ar[0], a1 = ar[1], a2 = ar[2], a3 = ar[3];
            FMA4(acc[0], a0.x, wv) FMA4(acc[1], a0.y, wv) FMA4(acc[2], a0.z, wv) FMA4(acc[3], a0.w, wv)
            FMA4(acc[4], a1.x, wv) FMA4(acc[5], a1.y, wv) FMA4(acc[6], a1.z, wv) FMA4(acc[7], a1.w, wv)
            FMA4(acc[8], a2.x, wv) FMA4(acc[9], a2.y, wv) FMA4(acc[10], a2.z, wv) FMA4(acc[11], a2.w, wv)
            FMA4(acc[12], a3.x, wv) FMA4(acc[13], a3.y, wv) FMA4(acc[14], a3.z, wv) FMA4(acc[15], a3.w, wv)
        }
    }
    #pragma unroll
    for (int b = 0; b < 16; ++b) {
        *(float4*)&part[((size_t)chunk * 16 + b) * 1024 + m] = acc[b];
    }
}

__global__ void hidden_kernel(const float* __restrict__ part, const float* __restrict__ b1,
                              float* __restrict__ hid) {
    int i = blockIdx.x * blockDim.x + threadIdx.x;
    if (i >= BSZ * MDIM) return;
    int b = i / MDIM, m = i % MDIM;
    float s = b1[m];
    for (int c = 0; c < NCHUNK; ++c) s += part[((size_t)c * 16 + b) * 1024 + m];
    hid[(size_t)b * MDIM + m] = fmaxf(s, 0.f);
}

__global__ void out_kernel(const float* __restrict__ hid, const float* __restrict__ w2,
                           const float* __restrict__ b2, float* __restrict__ out) {
    int i = blockIdx.x * blockDim.x + threadIdx.x;
    if (i >= BSZ * ODIM) return;
    int b = i / ODIM, o = i % ODIM;
    float s = b2[o];
    for (int m = 0; m < MDIM; ++m) s = fmaf(hid[b * MDIM + m], w2[m * ODIM + o], s);
    out[i] = s;
}

extern "C" void kernel_launch(void* const* d_in, const int* in_sizes, int n_in,
                              void* d_out, int out_size, void* d_ws, size_t ws_size,
                              hipStream_t stream) {
    const float* x      = (const float*)d_in[0];
    const int*   ei     = (const int*)d_in[1];
    const float* W1     = (const float*)d_in[4];
    const float* b1     = (const float*)d_in[5];
    const float* W2     = (const float*)d_in[6];
    const float* b2     = (const float*)d_in[7];
    const float* lin1w  = (const float*)d_in[8];
    const float* lin1b  = (const float*)d_in[9];
    const float* lin2w  = (const float*)d_in[10];
    const float* lin2b  = (const float*)d_in[11];
    float* out = (float*)d_out;

    // workspace layout (4B words), ~43.6 MB total
    int* wsi = (int*)d_ws;
    int* colhist = wsi;                               // NBUK*NB   = 524288
    int* rowhist = colhist + (size_t)NBUK * NB;       // NBUKR*NB  = 262144
    int* coltot  = rowhist + (size_t)NBUKR * NB;      // 1024
    int* colbase = coltot + NBUK;                     // 1024
    int* rowtot  = colbase + NBUK;                    // 512
    int* rowbase = rowtot + NBUKR;                    // 512
    float* dinv  = (float*)(rowbase + NBUKR);         // NN
    unsigned int* colbinned = (unsigned int*)(dinv + NN);        // NE
    unsigned char* rowbinned = (unsigned char*)(colbinned + NE); // NE bytes
    float* t1   = (float*)(rowbinned + NE);           // NN each
    float* t2   = t1 + NN;
    float* t3   = t2 + NN;
    float* t4   = t3 + NN;
    float* h1   = t4 + NN;                            // 8*NN
    float* bufA = h1 + 8 * (size_t)NN;                // 8*NN
    float* bufB = bufA + 8 * (size_t)NN;              // 8*NN
    float* accg = bufB + 8 * (size_t)NN;              // 8*NN (becomes h2)
    float* hid  = accg + 8 * (size_t)NN;              // 16384
    float* part = (float*)colbinned;                  // alias (dead by lin1): NE floats

    const int TB = 256;

    // build (no global atomics, no memsets)
    bin_count<<<NB, TB, 0, stream>>>(ei, colhist, rowhist);
    bin_scan<<<NBUK, TB, 0, stream>>>(colhist, coltot);
    bin_scan<<<NBUKR, TB, 0, stream>>>(rowhist, rowtot);
    base_scan<4><<<1, TB, 0, stream>>>(coltot, colbase);
    base_scan<2><<<1, TB, 0, stream>>>(rowtot, rowbase);
    bin_fill<<<NB, TB, 0, stream>>>(ei, colhist, rowhist, colbase, rowbase, colbinned, rowbinned);
    deg_finish<<<NBUKR, TB, 0, stream>>>(rowbinned, rowbase, rowtot, dinv);

    // layer 1
    cheb1_b<0><<<NBUK, TB, 0, stream>>>(colbinned, colbase, coltot, dinv, x, nullptr, t1);
    cheb1_b<1><<<NBUK, TB, 0, stream>>>(colbinned, colbase, coltot, dinv, t1, x, t2);
    cheb1_b<1><<<NBUK, TB, 0, stream>>>(colbinned, colbase, coltot, dinv, t2, t1, t3);
    cheb1_b<1><<<NBUK, TB, 0, stream>>>(colbinned, colbase, coltot, dinv, t3, t2, t4);
    h1_kernel<<<NN / TB, TB, 0, stream>>>(x, t1, t2, t3, t4, W1, b1, h1);

    // layer 2
    acc_init_kernel<<<NN * HID / TB, TB, 0, stream>>>(h1, W2, b2, accg);
    cheb8_b<0><<<NBUK, TB, 0, stream>>>(colbinned, colbase, coltot, dinv, h1, nullptr, bufA, W2 + 64, accg);
    cheb8_b<1><<<NBUK, TB, 0, stream>>>(colbinned, colbase, coltot, dinv, bufA, h1, bufB, W2 + 128, accg);
    cheb8_b<1><<<NBUK, TB, 0, stream>>>(colbinned, colbase, coltot, dinv, bufB, bufA, bufA, W2 + 192, accg);
    cheb8_b<2><<<NBUK, TB, 0, stream>>>(colbinned, colbase, coltot, dinv, bufA, bufB, nullptr, W2 + 256, accg);
    // accg now holds h2

    // dense
    lin1_kernel<<<NCHUNK, TB, 0, stream>>>(accg, lin1w, part);
    hidden_kernel<<<(BSZ * MDIM + TB - 1) / TB, TB, 0, stream>>>(part, lin1b, hid);
    out_kernel<<<(BSZ * ODIM + TB - 1) / TB, TB, 0, stream>>>(hid, lin2w, lin2b, out);
}

// Round 4
// 1080.706 us; speedup vs baseline: 7.3447x; 1.0652x over previous
//
#include <hip/hip_runtime.h>

#define NN 131072          // nodes (2^17)
#define NE 4194304         // edges
#define HID 8
#define BSZ 16
#define MDIM 1000
#define ODIM 34
#define FC 128             // f-chunk per lin1 block
#define NCHUNK 512         // 65536 / FC
#define NB 256             // edge-stripe blocks for binning
#define EPB (NE / NB)      // 16384
#define NBUK 1024          // col buckets (128 nodes each)
#define CNOD 128
#define NBUKR 512          // row buckets (256 nodes each)

typedef float f4v __attribute__((ext_vector_type(4)));

// ---------------- binning build (no global atomics) ----------------
__global__ __launch_bounds__(512) void bin_count(const int* __restrict__ ei,
                                                 int* __restrict__ colhist,
                                                 int* __restrict__ rowhist) {
    __shared__ int ch[NBUK];
    __shared__ int rh[NBUKR];
    int b = blockIdx.x, t = threadIdx.x;
    for (int i = t; i < NBUK; i += 512) ch[i] = 0;
    for (int i = t; i < NBUKR; i += 512) rh[i] = 0;
    __syncthreads();
    int base = b * EPB;
    for (int k = t; k < EPB; k += 512) {
        int e = base + k;
        int r = __builtin_nontemporal_load(&ei[e]);
        int c = __builtin_nontemporal_load(&ei[NE + e]);
        if (r != c) { atomicAdd(&ch[c >> 7], 1); atomicAdd(&rh[r >> 8], 1); }
    }
    __syncthreads();
    for (int i = t; i < NBUK; i += 512) colhist[b * NBUK + i] = ch[i];
    for (int i = t; i < NBUKR; i += 512) rowhist[b * NBUKR + i] = rh[i];
}

// per-bucket scan across NB stripes; hist[b][bucket] -> local exclusive offsets
__global__ __launch_bounds__(256) void bin_scan(int* __restrict__ hist,
                                                int* __restrict__ tot, int nbuckets) {
    __shared__ int s[NB];
    int i = blockIdx.x, t = threadIdx.x;
    int v = hist[t * nbuckets + i];
    s[t] = v; __syncthreads();
    for (int off = 1; off < NB; off <<= 1) {
        int x = (t >= off) ? s[t - off] : 0;
        __syncthreads(); s[t] += x; __syncthreads();
    }
    hist[t * nbuckets + i] = s[t] - v;
    if (t == NB - 1) tot[i] = s[t];
}

template <int M>
__global__ __launch_bounds__(256) void base_scan(const int* __restrict__ tot,
                                                 int* __restrict__ basev) {
    __shared__ int s[256];
    int t = threadIdx.x;
    int v[M]; int ps = 0;
    #pragma unroll
    for (int q = 0; q < M; ++q) { v[q] = tot[t * M + q]; ps += v[q]; }
    s[t] = ps; __syncthreads();
    for (int off = 1; off < 256; off <<= 1) {
        int x = (t >= off) ? s[t - off] : 0;
        __syncthreads(); s[t] += x; __syncthreads();
    }
    int run = s[t] - ps;
    #pragma unroll
    for (int q = 0; q < M; ++q) { basev[t * M + q] = run; run += v[q]; }
}

__global__ __launch_bounds__(512) void bin_fill(const int* __restrict__ ei,
                                                const int* __restrict__ colhist,
                                                const int* __restrict__ rowhist,
                                                const int* __restrict__ colbase,
                                                const int* __restrict__ rowbase,
                                                unsigned int* __restrict__ colbinned,
                                                unsigned char* __restrict__ rowbinned) {
    __shared__ int cc[NBUK];
    __shared__ int rc[NBUKR];
    int b = blockIdx.x, t = threadIdx.x;
    for (int i = t; i < NBUK; i += 512) cc[i] = colbase[i] + colhist[b * NBUK + i];
    for (int i = t; i < NBUKR; i += 512) rc[i] = rowbase[i] + rowhist[b * NBUKR + i];
    __syncthreads();
    int base = b * EPB;
    for (int k = t; k < EPB; k += 512) {
        int e = base + k;
        int r = __builtin_nontemporal_load(&ei[e]);
        int c = __builtin_nontemporal_load(&ei[NE + e]);
        if (r != c) {
            int p = atomicAdd(&cc[c >> 7], 1);
            colbinned[p] = ((unsigned)r << 7) | (unsigned)(c & 127);
            int q = atomicAdd(&rc[r >> 8], 1);
            rowbinned[q] = (unsigned char)(r & 255);
        }
    }
}

// degree histogram per row bucket -> dinv, rinv, sx (scaled x)
__global__ __launch_bounds__(256) void deg_finish(const unsigned char* __restrict__ rowbinned,
                                                  const int* __restrict__ rowbase,
                                                  const int* __restrict__ rowtot,
                                                  const float* __restrict__ x,
                                                  float* __restrict__ dinv,
                                                  float* __restrict__ rinv,
                                                  float* __restrict__ sx) {
    __shared__ int cnt[256];
    int b = blockIdx.x, t = threadIdx.x;
    cnt[t] = 0; __syncthreads();
    int s0 = rowbase[b], n = rowtot[b];
    for (int i = t; i < n; i += 256) atomicAdd(&cnt[rowbinned[s0 + i]], 1);
    __syncthreads();
    int d = cnt[t];
    int node = b * 256 + t;
    float dn = (d > 0) ? rsqrtf((float)d) : 0.f;
    dinv[node] = dn;
    rinv[node] = (d > 0) ? sqrtf((float)d) : 1.f;
    sx[node] = ((d > 0) ? dn : 1.f) * x[node];
}

// ---------------- layer 1 (scalar, scaled w-space) ----------------
// w_k = s_n * T_k ; gather reads w_in[r] (sources always have deg>0 => w = dinv*T)
template <int MODE>   // 0: first (T1), 1: recurrence
__global__ __launch_bounds__(512) void cheb1_b(const unsigned int* __restrict__ colbinned,
                                               const int* __restrict__ colbase,
                                               const int* __restrict__ coltot,
                                               const float* __restrict__ dinv,
                                               const float* __restrict__ w_in,
                                               const float* __restrict__ wp2,
                                               float* __restrict__ w_out) {
    __shared__ float acc[CNOD];
    int b = blockIdx.x, t = threadIdx.x;
    if (t < CNOD) acc[t] = 0.f;
    __syncthreads();
    int s0 = colbase[b], n = coltot[b];
    for (int i = t; i < n; i += 512) {
        unsigned int rec = __builtin_nontemporal_load(&colbinned[s0 + i]);
        atomicAdd(&acc[rec & 127], w_in[rec >> 7]);
    }
    __syncthreads();
    if (t < CNOD) {
        int node = b * CNOD + t;
        float dn = dinv[node];
        float lh;
        if (dn > 0.f) lh = -dn * acc[t]; else lh = -w_in[node];
        float s = (dn > 0.f) ? dn : 1.f;
        w_out[node] = (MODE == 0) ? s * lh : s * (2.f * lh) - wp2[node];
    }
}

// h1 = relu(sum Tk W1[k]) ; writes sh1 = s*h1 and accg = b2 + h1@W2[0]
__global__ __launch_bounds__(256) void h1_kernel(const float* __restrict__ x,
        const float* __restrict__ wt1, const float* __restrict__ wt2,
        const float* __restrict__ wt3, const float* __restrict__ wt4,
        const float* __restrict__ dinv, const float* __restrict__ rinv,
        const float* __restrict__ W1, const float* __restrict__ b1,
        const float* __restrict__ W20, const float* __restrict__ b2,
        float* __restrict__ sh1, float* __restrict__ accg) {
    int n = blockIdx.x * 256 + threadIdx.x;
    float rn = rinv[n], dn = dinv[n];
    float s = (dn > 0.f) ? dn : 1.f;
    float T0 = x[n], T1 = wt1[n] * rn, T2 = wt2[n] * rn, T3 = wt3[n] * rn, T4 = wt4[n] * rn;
    float h[HID];
    #pragma unroll
    for (int j = 0; j < HID; ++j) {
        float v = b1[j] + T0 * W1[j] + T1 * W1[8 + j] + T2 * W1[16 + j]
                + T3 * W1[24 + j] + T4 * W1[32 + j];
        h[j] = fmaxf(v, 0.f);
    }
    f4v sv0, sv1, av0, av1;
    #pragma unroll
    for (int j = 0; j < 4; ++j) { sv0[j] = s * h[j]; sv1[j] = s * h[4 + j]; }
    #pragma unroll
    for (int o = 0; o < HID; ++o) {
        float v = b2[o];
        #pragma unroll
        for (int j = 0; j < HID; ++j) v = fmaf(h[j], W20[j * 8 + o], v);
        if (o < 4) av0[o] = v; else av1[o - 4] = v;
    }
    *(f4v*)&sh1[n * 8] = sv0;  *(f4v*)&sh1[n * 8 + 4] = sv1;
    *(f4v*)&accg[n * 8] = av0; *(f4v*)&accg[n * 8 + 4] = av1;
}

// ---------------- layer 2 (8-wide, scaled w-space, fused W2[k]) ----------------
template <int MODE>   // 0 first, 1 mid, 2 final (relu, no w_out)
__global__ __launch_bounds__(512) void cheb8_b(const unsigned int* __restrict__ colbinned,
        const int* __restrict__ colbase, const int* __restrict__ coltot,
        const float* __restrict__ dinv, const float* __restrict__ rinv,
        const float* __restrict__ w_in, const float* __restrict__ wp2,
        float* __restrict__ w_out, const float* __restrict__ Wk,
        float* __restrict__ accg) {
    __shared__ float acc[HID][CNOD];   // SoA: bank = cl&31
    __shared__ float vb[CNOD][HID];
    __shared__ float wk[64];
    int b = blockIdx.x, t = threadIdx.x;
    if (t < 64) wk[t] = Wk[t];
    for (int i = t; i < CNOD * HID; i += 512) ((float*)acc)[i] = 0.f;
    __syncthreads();
    int s0 = colbase[b], n = coltot[b];
    for (int i = t; i < n; i += 512) {
        unsigned int rec = __builtin_nontemporal_load(&colbinned[s0 + i]);
        int r = rec >> 7, cl = rec & 127;
        const f4v* sp = (const f4v*)&w_in[r * 8];
        f4v a = sp[0], c = sp[1];
        atomicAdd(&acc[0][cl], a.x); atomicAdd(&acc[1][cl], a.y);
        atomicAdd(&acc[2][cl], a.z); atomicAdd(&acc[3][cl], a.w);
        atomicAdd(&acc[4][cl], c.x); atomicAdd(&acc[5][cl], c.y);
        atomicAdd(&acc[6][cl], c.z); atomicAdd(&acc[7][cl], c.w);
    }
    __syncthreads();
    #pragma unroll
    for (int k2 = 0; k2 < 2; ++k2) {
        int idx = k2 * 512 + t;
        int nl = idx >> 3, jj = idx & 7;
        int node = b * CNOD + nl;
        float dn = dinv[node];
        float lh;
        if (dn > 0.f) lh = -dn * acc[jj][nl]; else lh = -w_in[node * 8 + jj];
        float T;
        if (MODE == 0) {
            T = lh;
            w_out[node * 8 + jj] = (dn > 0.f) ? dn * lh : lh;
        } else if (MODE == 1) {
            float w = ((dn > 0.f) ? dn : 1.f) * (2.f * lh) - wp2[node * 8 + jj];
            w_out[node * 8 + jj] = w;
            T = w * rinv[node];
        } else {
            T = 2.f * lh - wp2[node * 8 + jj] * rinv[node];
        }
        vb[nl][jj] = T;
    }
    __syncthreads();
    #pragma unroll
    for (int k2 = 0; k2 < 2; ++k2) {
        int idx = k2 * 512 + t;
        int nl = idx >> 3, jj = idx & 7;
        int node = b * CNOD + nl;
        float sum = 0.f;
        #pragma unroll
        for (int q = 0; q < HID; ++q) sum = fmaf(vb[nl][q], wk[q * 8 + jj], sum);
        float r2 = accg[node * 8 + jj] + sum;
        accg[node * 8 + jj] = (MODE == 2) ? fmaxf(r2, 0.f) : r2;
    }
}

// ---------------- dense layers ----------------
__global__ __launch_bounds__(256) void lin1_kernel(const float* __restrict__ h2,
                                                   const float* __restrict__ w,
                                                   float* __restrict__ part) {
    int chunk = blockIdx.x, t = threadIdx.x;
    int fbase = chunk * FC;
    __shared__ __align__(16) float a[FC * 20];
    for (int i = t; i < BSZ * FC; i += 256) {
        int bb = i >> 7, f = i & (FC - 1);
        a[f * 20 + bb] = h2[(size_t)bb * 65536 + fbase + f];
    }
    __syncthreads();
    f4v acc[16];
    #pragma unroll
    for (int bb = 0; bb < 16; ++bb) acc[bb] = (f4v)(0.f);
    int m = t * 4;
    if (m < MDIM) {
        for (int f = 0; f < FC; ++f) {
            f4v wv = __builtin_nontemporal_load((const f4v*)&w[(size_t)(fbase + f) * MDIM + m]);
            const f4v* ar = (const f4v*)&a[f * 20];
            f4v a0 = ar[0], a1 = ar[1], a2 = ar[2], a3 = ar[3];
            acc[0] += a0.x * wv;  acc[1] += a0.y * wv;  acc[2] += a0.z * wv;  acc[3] += a0.w * wv;
            acc[4] += a1.x * wv;  acc[5] += a1.y * wv;  acc[6] += a1.z * wv;  acc[7] += a1.w * wv;
            acc[8] += a2.x * wv;  acc[9] += a2.y * wv;  acc[10] += a2.z * wv; acc[11] += a2.w * wv;
            acc[12] += a3.x * wv; acc[13] += a3.y * wv; acc[14] += a3.z * wv; acc[15] += a3.w * wv;
        }
    }
    #pragma unroll
    for (int bb = 0; bb < 16; ++bb) {
        __builtin_nontemporal_store(acc[bb], (f4v*)&part[((size_t)chunk * 16 + bb) * 1024 + m]);
    }
}

__global__ __launch_bounds__(256) void hidden1(const float* __restrict__ part,
                                               float* __restrict__ part2) {
    int g = blockIdx.x >> 6;
    int off = (blockIdx.x & 63) * 256 + threadIdx.x;   // 0..16383
    float s = 0.f;
    const float* p = part + (size_t)g * 64 * 16384 + off;
    for (int c = 0; c < 64; ++c) s += __builtin_nontemporal_load(&p[c * 16384]);
    part2[g * 16384 + off] = s;
}

__global__ __launch_bounds__(256) void hidden2(const float* __restrict__ part2,
                                               const float* __restrict__ lb,
                                               float* __restrict__ hid) {
    int off = blockIdx.x * 256 + threadIdx.x;
    int b = off >> 10, m = off & 1023;
    if (m >= MDIM) return;
    float s = lb[m];
    for (int g = 0; g < 8; ++g) s += part2[g * 16384 + off];
    hid[b * MDIM + m] = fmaxf(s, 0.f);
}

__global__ void out_kernel(const float* __restrict__ hid, const float* __restrict__ w2,
                           const float* __restrict__ b2, float* __restrict__ out) {
    int i = blockIdx.x * blockDim.x + threadIdx.x;
    if (i >= BSZ * ODIM) return;
    int b = i / ODIM, o = i % ODIM;
    float s = b2[o];
    for (int m = 0; m < MDIM; ++m) s = fmaf(hid[b * MDIM + m], w2[m * ODIM + o], s);
    out[i] = s;
}

extern "C" void kernel_launch(void* const* d_in, const int* in_sizes, int n_in,
                              void* d_out, int out_size, void* d_ws, size_t ws_size,
                              hipStream_t stream) {
    const float* x      = (const float*)d_in[0];
    const int*   ei     = (const int*)d_in[1];
    const float* W1     = (const float*)d_in[4];
    const float* b1     = (const float*)d_in[5];
    const float* W2     = (const float*)d_in[6];
    const float* b2     = (const float*)d_in[7];
    const float* lin1w  = (const float*)d_in[8];
    const float* lin1b  = (const float*)d_in[9];
    const float* lin2w  = (const float*)d_in[10];
    const float* lin2b  = (const float*)d_in[11];
    float* out = (float*)d_out;

    // ---- workspace layout (~41.6 MB) ----
    // front block (dead by lin1, aliased by part = 8388608 words exactly):
    unsigned int* colbinned = (unsigned int*)d_ws;               // NE
    unsigned char* rowbinned = (unsigned char*)(colbinned + NE); // NE bytes
    float* wA   = (float*)(rowbinned + NE);                      // 8*NN
    float* wB   = wA + 8 * (size_t)NN;                           // 8*NN
    float* sh1  = wB + 8 * (size_t)NN;                           // 8*NN
    // persistent tail:
    float* wt1  = sh1 + 8 * (size_t)NN;                          // NN each
    float* wt2  = wt1 + NN;
    float* wt3  = wt2 + NN;
    float* wt4  = wt3 + NN;
    float* sx   = wt4 + NN;
    float* dinv = sx + NN;
    float* rinv = dinv + NN;
    int* colhist = (int*)(rinv + NN);                            // NB*NBUK
    int* rowhist = colhist + (size_t)NB * NBUK;                  // NB*NBUKR
    int* coltot  = rowhist + (size_t)NB * NBUKR;                 // NBUK
    int* colbase = coltot + NBUK;                                // NBUK
    int* rowtot  = colbase + NBUK;                               // NBUKR
    int* rowbase = rowtot + NBUKR;                               // NBUKR
    float* accg  = (float*)(rowbase + NBUKR);                    // 8*NN
    float* hid   = accg + 8 * (size_t)NN;                        // BSZ*1024
    float* part2 = hid + BSZ * 1024;                             // 8*16384
    float* part  = (float*)colbinned;                            // alias front block

    // build
    bin_count<<<NB, 512, 0, stream>>>(ei, colhist, rowhist);
    bin_scan<<<NBUK, NB, 0, stream>>>(colhist, coltot, NBUK);
    bin_scan<<<NBUKR, NB, 0, stream>>>(rowhist, rowtot, NBUKR);
    base_scan<4><<<1, 256, 0, stream>>>(coltot, colbase);
    base_scan<2><<<1, 256, 0, stream>>>(rowtot, rowbase);
    bin_fill<<<NB, 512, 0, stream>>>(ei, colhist, rowhist, colbase, rowbase, colbinned, rowbinned);
    deg_finish<<<NBUKR, 256, 0, stream>>>(rowbinned, rowbase, rowtot, x, dinv, rinv, sx);

    // layer 1 (scaled space)
    cheb1_b<0><<<NBUK, 512, 0, stream>>>(colbinned, colbase, coltot, dinv, sx, nullptr, wt1);
    cheb1_b<1><<<NBUK, 512, 0, stream>>>(colbinned, colbase, coltot, dinv, wt1, sx, wt2);
    cheb1_b<1><<<NBUK, 512, 0, stream>>>(colbinned, colbase, coltot, dinv, wt2, wt1, wt3);
    cheb1_b<1><<<NBUK, 512, 0, stream>>>(colbinned, colbase, coltot, dinv, wt3, wt2, wt4);
    h1_kernel<<<NN / 256, 256, 0, stream>>>(x, wt1, wt2, wt3, wt4, dinv, rinv,
                                            W1, b1, W2, b2, sh1, accg);

    // layer 2 (scaled space, fused W2[k] accumulation)
    cheb8_b<0><<<NBUK, 512, 0, stream>>>(colbinned, colbase, coltot, dinv, rinv,
                                         sh1, nullptr, wA, W2 + 64, accg);
    cheb8_b<1><<<NBUK, 512, 0, stream>>>(colbinned, colbase, coltot, dinv, rinv,
                                         wA, sh1, wB, W2 + 128, accg);
    cheb8_b<1><<<NBUK, 512, 0, stream>>>(colbinned, colbase, coltot, dinv, rinv,
                                         wB, wA, wA, W2 + 192, accg);
    cheb8_b<2><<<NBUK, 512, 0, stream>>>(colbinned, colbase, coltot, dinv, rinv,
                                         wA, wB, nullptr, W2 + 256, accg);
    // accg now holds h2

    // dense
    lin1_kernel<<<NCHUNK, 256, 0, stream>>>(accg, lin1w, part);
    hidden1<<<512, 256, 0, stream>>>(part, part2);
    hidden2<<<64, 256, 0, stream>>>(part2, lin1b, hid);
    out_kernel<<<3, 256, 0, stream>>>(hid, lin2w, lin2b, out);
}